// Round 1
// baseline (224.179 us; speedup 1.0000x reference)
//
#include <hip/hip_runtime.h>

// ROI max pooling (Fast R-CNN style, PyTorch AdaptiveMaxPool bin arithmetic)
// features: [1, 512, 64, 64] fp32   proposals: [2000, 4] fp32 (x1,y1,x2,y2 px)
// out: [2000, 512, 7, 7] fp32
//
// props_cell = floor(prop / 16)
// bin starts = lo + (i*L)/7 ; ends = lo + ceil((i+1)*L/7), L = hi - lo
// out[n,c,i,j] = max over feats[c, hs_i:he_i, ws_j:we_j]  (NEG if empty)

#define NCH   512
#define FH    64
#define FW    64
#define NPROP 2000
#define ROI   7
#define OUT_PER_PROP (NCH * ROI * ROI)   // 25088 = 14 * 256 * 7

__global__ __launch_bounds__(256) void roipool_kernel(
    const float* __restrict__ feats,   // [512,64,64]
    const float* __restrict__ props,   // [2000,4]
    float* __restrict__ out)           // [2000,512,7,7]
{
    const int n = blockIdx.x;

    __shared__ int s_hs[ROI], s_he[ROI], s_ws[ROI], s_we[ROI];

    if (threadIdx.x < ROI) {
        const int i = threadIdx.x;
        // floor(prop/16): /16 is exact in fp32 (power of 2), coords >= 0
        const int x1 = (int)floorf(props[n * 4 + 0] * 0.0625f);
        const int y1 = (int)floorf(props[n * 4 + 1] * 0.0625f);
        const int x2 = (int)floorf(props[n * 4 + 2] * 0.0625f);
        const int y2 = (int)floorf(props[n * 4 + 3] * 0.0625f);
        const int Lh = y2 - y1;
        const int Lw = x2 - x1;
        // PyTorch adaptive bins; clamp to [0, H) to match the reference mask
        int hs = y1 + (i * Lh) / ROI;
        int he = y1 + ((i + 1) * Lh + (ROI - 1)) / ROI;
        int ws = x1 + (i * Lw) / ROI;
        int we = x1 + ((i + 1) * Lw + (ROI - 1)) / ROI;
        s_hs[i] = max(hs, 0);
        s_he[i] = min(he, FH);
        s_ws[i] = max(ws, 0);
        s_we[i] = min(we, FW);
    }
    __syncthreads();

    const float NEG = -3.402823466e+38f;  // finfo(float32).min

    const int base = blockIdx.y * (256 * ROI);
    float* outn = out + (size_t)n * OUT_PER_PROP;

#pragma unroll
    for (int k = 0; k < ROI; ++k) {
        const int idx = base + k * 256 + threadIdx.x;   // < 25088 by construction
        const int c   = idx / (ROI * ROI);
        const int bin = idx - c * (ROI * ROI);
        const int bi  = bin / ROI;        // h bin
        const int bj  = bin - bi * ROI;   // w bin

        const int hs = s_hs[bi], he = s_he[bi];
        const int ws = s_ws[bj], we = s_we[bj];

        const float* __restrict__ fp = feats + (size_t)c * (FH * FW);

        float acc = NEG;
        for (int h = hs; h < he; ++h) {
            const float* row = fp + h * FW;
            for (int w = ws; w < we; ++w) {
                acc = fmaxf(acc, row[w]);
            }
        }
        outn[idx] = acc;
    }
}

extern "C" void kernel_launch(void* const* d_in, const int* in_sizes, int n_in,
                              void* d_out, int out_size, void* d_ws, size_t ws_size,
                              hipStream_t stream) {
    const float* feats = (const float*)d_in[0];   // [1,512,64,64]
    const float* props = (const float*)d_in[1];   // [2000,4]
    float* out = (float*)d_out;                   // [2000,512,7,7]

    dim3 grid(NPROP, OUT_PER_PROP / (256 * ROI));  // (2000, 14)
    dim3 block(256);
    roipool_kernel<<<grid, block, 0, stream>>>(feats, props, out);
}